// Round 16
// baseline (263.203 us; speedup 1.0000x reference)
//
#include <hip/hip_runtime.h>

#define LOG2E 1.44269504088896340736f

typedef __attribute__((ext_vector_type(8))) short short8;
typedef __attribute__((ext_vector_type(4))) float float4v;
typedef __attribute__((ext_vector_type(2))) float float2v;
typedef __attribute__((ext_vector_type(2))) int int2v;
typedef __attribute__((ext_vector_type(4))) int int4v;

__device__ inline unsigned short f2bf(float f) {
    union { float f; unsigned u; } v; v.f = f;
    unsigned r = v.u + 0x7fffu + ((v.u >> 16) & 1u);
    return (unsigned short)(r >> 16);
}
__device__ inline float bf2f(unsigned short u) {
    union { unsigned u; float f; } v; v.u = ((unsigned)u) << 16;
    return v.f;
}
// pack hi16(a)|hi16(b)<<16 with +0x8000 rounding (2 adds + 1 perm); a = low half
__device__ inline unsigned pk_bf16(float a, float b) {
    union { float f; unsigned u; } ua, ub; ua.f = a; ub.f = b;
    return __builtin_amdgcn_perm(ub.u + 0x8000u, ua.u + 0x8000u, 0x07060302u);
}
// hardware packed cvt: dst = {lo16: bf16(a), hi16: bf16(b)} (RNE), 1 VALU op
__device__ inline unsigned cvtpk_bf16(float a, float b) {
    unsigned r;
    asm("v_cvt_pk_bf16_f32 %0, %1, %2" : "=v"(r) : "v"(a), "v"(b));
    return r;
}

// ---------------------------------------------------------------------------
// Kernel 0: convert weights to bf16, concatenated Wbf[320][256]
// rows 0-31 = wq, 32-63 = wk, 64-319 = wv.  grid 80 x 256.
// ---------------------------------------------------------------------------
__global__ void wcvt_kernel(const float* __restrict__ wq, const float* __restrict__ wk,
                            const float* __restrict__ wv, unsigned short* __restrict__ Wbf)
{
    int idx = blockIdx.x * 256 + threadIdx.x;     // 20480 float4s
    int e4  = idx * 4;
    int row = e4 >> 8, col = e4 & 255;
    const float* src = (row < 32) ? (wq + row * 256 + col)
                     : (row < 64) ? (wk + (row - 32) * 256 + col)
                                  : (wv + (row - 64) * 256 + col);
    float4v v = *(const float4v*)src;
    int2v p;
    p.x = (unsigned)f2bf(v[0]) | ((unsigned)f2bf(v[1]) << 16);
    p.y = (unsigned)f2bf(v[2]) | ((unsigned)f2bf(v[3]) << 16);
    *(int2v*)(Wbf + e4) = p;
}

// ---------------------------------------------------------------------------
// Kernel 1: projections — 64-pixel tiles, grid 256.  Byte-identical to R13-15
// (best measured rest).  Phase 1 COALESCED; Wbf reads; LDS pad 266.
// ---------------------------------------------------------------------------
__launch_bounds__(512, 2)
__global__ void proj_kernel(const float* __restrict__ a_p, const float* __restrict__ b_p,
                            const float* __restrict__ c_p,
                            const float* __restrict__ bq, const float* __restrict__ bk,
                            const float* __restrict__ bv,
                            const unsigned short* __restrict__ Wbf,
                            unsigned short* __restrict__ Qg, unsigned short* __restrict__ Kg,
                            unsigned short* __restrict__ Vg)
{
    __shared__ __align__(16) unsigned short At[64 * 266];   // (i, c) bf16, pad 266
    __shared__ __align__(16) unsigned short Bt[64 * 266];
    __shared__ float bias[320];
    __shared__ float cdl[64];

    const int t    = threadIdx.x;
    const int blk  = blockIdx.x;
    const int b    = blk & 3;
    const int tile = blk >> 2;
    const int i0   = tile * 64;
    const int lane = t & 63;
    const int w    = t >> 6;
    const int q    = lane >> 4;
    const int n    = lane & 15;
    const int it   = w & 3;     // i-tile
    const int mh   = w >> 2;    // m-half (0: mt 0-9, 1: mt 10-19)

    // ---- phase 1: stage a,b tiles transposed to LDS (i, c) bf16, COALESCED ----
    {
        const int arr = t >> 8, tt = t & 255;
        unsigned* dst = (unsigned*)(arr ? Bt : At);
        const float* base = (arr ? b_p : a_p) + (size_t)b * 256 * 4096 + i0;
#pragma unroll
        for (int r = 0; r < 8; ++r) {
            int task = r * 256 + tt;
            int cp = task >> 4, px4 = (task & 15) * 4;
            const float* s0 = base + (size_t)(2 * cp) * 4096 + px4;
            float4v r0 = *(const float4v*)s0;
            float4v r1 = *(const float4v*)(s0 + 4096);
#pragma unroll
            for (int k = 0; k < 4; ++k)
                dst[(px4 + k) * 133 + cp] = pk_bf16(r0[k], r1[k]);
        }
        if (t < 320) bias[t] = (t < 32) ? bq[t] : (t < 64) ? bk[t - 32] : bv[t - 64];
        else if (t < 384) cdl[t - 320] = c_p[b * 16384 + tile * 256 + (t - 320) * 2];
    }
    __syncthreads();

    // ---- phase 2: MFMA (A = Wbf rows, B = X^T) ----
    float4v acc[10];
#pragma unroll
    for (int j = 0; j < 10; ++j) acc[j] = (float4v){0.f, 0.f, 0.f, 0.f};

#pragma unroll 2
    for (int kc = 0; kc < 8; ++kc) {
        short8 xa = *(const short8*)&At[(it * 16 + n) * 266 + kc * 32 + q * 8];
        short8 xb = xa;
        if (mh == 0)
            xb = *(const short8*)&Bt[(it * 16 + n) * 266 + kc * 32 + q * 8];
#pragma unroll
        for (int j = 0; j < 10; ++j) {
            int mt = mh * 10 + j;
            short8 wf = *(const short8*)(Wbf + (size_t)(mt * 16 + n) * 256 + kc * 32 + q * 8);
            short8 bsel = (mt == 2 || mt == 3) ? xb : xa;
            acc[j] = __builtin_amdgcn_mfma_f32_16x16x32_bf16(wf, bsel, acc[j], 0, 0, 0);
        }
    }
    __syncthreads();   // all LDS reads done; At/Bt reusable as staging

    // ---- phase 3a: frags -> LDS staging ----
    unsigned short* QKst = At;   // [i][72] ushort (row 144B, 16B-aligned)
    unsigned short* Vst  = Bt;   // [jb][c][32] ushort = 16384
    {
        const float cdq = cdl[it * 16 + n] * LOG2E;
#pragma unroll
        for (int j = 0; j < 10; ++j) {
            int mt = mh * 10 + j;
            float4v bv4 = *(const float4v*)&bias[mt * 16 + q * 4];
            float v0 = acc[j][0] + bv4[0], v1 = acc[j][1] + bv4[1];
            float v2 = acc[j][2] + bv4[2], v3 = acc[j][3] + bv4[3];
            if (mt < 2) {        // Q: scale by cd*log2e
                v0 *= cdq; v1 *= cdq; v2 *= cdq; v3 *= cdq;
                int2v pk; pk.x = (int)pk_bf16(v0, v1); pk.y = (int)pk_bf16(v2, v3);
                *(int2v*)&QKst[(it * 16 + n) * 72 + mt * 16 + q * 4] = pk;
            } else if (mt < 4) { // K
                int2v pk; pk.x = (int)pk_bf16(v0, v1); pk.y = (int)pk_bf16(v2, v3);
                *(int2v*)&QKst[(it * 16 + n) * 72 + mt * 16 + q * 4] = pk;
            } else {             // V: c = mt*16-64+q*4+r, p fixed per lane
                int p = ((n >> 2) * 8) + ((it & 1) * 4) + (n & 3);
                int cbase = mt * 16 - 64 + q * 4;
                int jb = it >> 1;
                Vst[((jb * 256) + cbase + 0) * 32 + p] = f2bf(v0);
                Vst[((jb * 256) + cbase + 1) * 32 + p] = f2bf(v1);
                Vst[((jb * 256) + cbase + 2) * 32 + p] = f2bf(v2);
                Vst[((jb * 256) + cbase + 3) * 32 + p] = f2bf(v3);
            }
        }
    }
    __syncthreads();

    // ---- phase 3b: coalesced global writes (16B per lane) ----
    {   // Q/K: 64 i x 64 m; thread: i = t>>3, 8-m chunk h8 = t&7
        int i = t >> 3, h8 = t & 7;
        int4v v = *(const int4v*)&QKst[i * 72 + h8 * 8];
        unsigned short* dstp = (h8 < 4)
            ? Qg + (size_t)(b * 4096 + i0 + i) * 32 + h8 * 8
            : Kg + (size_t)(b * 4096 + i0 + i) * 32 + (h8 - 4) * 8;
        *(int4v*)dstp = v;
    }
    {   // V: 32KB flat copy (Vst inner layout == Vg inner layout)
#pragma unroll
        for (int k = 0; k < 4; ++k) {
            int flat = k * 512 + t;              // 16B units
            int4v v = *(const int4v*)&Vst[flat * 8];
            int jb = flat >> 10;                 // 1024 x 16B per jblk
            *(int4v*)(Vg + (size_t)(b * 128 + tile * 2 + jb) * 8192 + (flat & 1023) * 8) = v;
        }
    }
}

// ---------------------------------------------------------------------------
// Kernel 2: flash attention, 3-split {48,48,32}, WAVE-OWNS-I-TILE partition.
// R14/15 lesson: cross-wave P-sharing (wave = c-slice) costs a barrier-
// serialized LDS round trip per iter (~2900 cyc/iter vs ~600 compute; both
// barrier flavors identical).  Repartition: wave w owns i-tile w — computes
// S(own) (2 MFMA + 8 exp2: keeps the 4x VALU cut) AND PV(own ig, ALL 16
// c-tiles, 16 MFMA) with P in REGISTERS.  No LDS, no barriers, R8 pipeline.
// V frags read 4x/block (L1/L2-resident, HBM 7% - cheap); same MFMA count.
// vf: 2x4-frag rotation (32 VGPR); arch ~90 + 64 AGPR < 170 cap @ 3 blk/CU.
// ---------------------------------------------------------------------------
__launch_bounds__(256, 3)
__global__ void attn_kernel(const unsigned short* __restrict__ Qg,
                            const unsigned short* __restrict__ Kg,
                            const unsigned short* __restrict__ Vg,
                            unsigned short* __restrict__ Opart, float* __restrict__ lsum)
{
    const int t    = threadIdx.x;
    const int blk  = blockIdx.x;
    const int b    = blk & 3;            // XCD = blk%8 -> b fixed per XCD
    const int rt   = (blk >> 2) & 63;
    const int s    = blk >> 8;           // 0..2
    const int ni   = (s == 2) ? 32 : 48; // iters this split
    const int lidx = (s << 8) | (rt << 2) | b;    // logical index for Opart/lsum
    const int i0   = rt * 64;
    const int lane = t & 63;
    const int w    = t >> 6;
    const int q    = lane >> 4;
    const int n    = lane & 15;

    // Q B-frag for OWN i-tile (ig == w)
    short8 qf = *(const short8*)(Qg + (size_t)(b * 4096 + i0 + w * 16 + n) * 32 + q * 8);

    float4v acc[16];     // [ct] — own i-tile x 16 c-tiles (64 AGPR)
#pragma unroll
    for (int ct = 0; ct < 16; ++ct) acc[ct] = (float4v){0.f, 0.f, 0.f, 0.f};
    float lsc = 0.f;     // rowsum partial for own ig

    const float4v m16v = (float4v){-16.f, -16.f, -16.f, -16.f};

    // split s covers j rows [s*1536, s*1536 + ni*32)
    const unsigned short* kb = Kg + (size_t)(b * 4096 + s * 1536 + n) * 32 + q * 8;
    // V base for c-tile 0: [b][jblk][c][p], c = ct*16 + n, p = q*8..+8
    const unsigned short* vb = Vg + ((size_t)((b * 128 + s * 48) * 256 + n)) * 32 + q * 8;

    // ---- prologue: K(0); S(0,own) -> pfc; K(1); V(0) g0 -> vfP ----
    short8 kf0 = *(const short8*)(kb);
    short8 kf1 = *(const short8*)(kb + 512);

    short8 pfc;
    {
        float4v s0 = __builtin_amdgcn_mfma_f32_16x16x32_bf16(kf0, qf, m16v, 0, 0, 0);
        float4v s1 = __builtin_amdgcn_mfma_f32_16x16x32_bf16(kf1, qf, m16v, 0, 0, 0);
        kf0 = *(const short8*)(kb + 1024);   // K(1)
        kf1 = *(const short8*)(kb + 1536);
        float p0 = __builtin_amdgcn_exp2f(s0[0]), p1 = __builtin_amdgcn_exp2f(s0[1]);
        float p2 = __builtin_amdgcn_exp2f(s0[2]), p3 = __builtin_amdgcn_exp2f(s0[3]);
        float p4 = __builtin_amdgcn_exp2f(s1[0]), p5 = __builtin_amdgcn_exp2f(s1[1]);
        float p6 = __builtin_amdgcn_exp2f(s1[2]), p7 = __builtin_amdgcn_exp2f(s1[3]);
        lsc += ((p0 + p1) + (p2 + p3)) + ((p4 + p5) + (p6 + p7));
        union { short8 s8; unsigned u[4]; } pf_;
        pf_.u[0] = cvtpk_bf16(p0, p1);   // k = jt*4 + r order (matches V perm)
        pf_.u[1] = cvtpk_bf16(p2, p3);
        pf_.u[2] = cvtpk_bf16(p4, p5);
        pf_.u[3] = cvtpk_bf16(p6, p7);
        pfc = pf_.s8;
    }
    short8 vfP[4], vfQ[4];
#pragma unroll
    for (int k = 0; k < 4; ++k)
        vfP[k] = *(const short8*)(vb + k * 512);   // V(0) ct 0..3
    kb += 2048;    // points at K(2)

    // ---- main loop: ni-1 iters; PV(t) fully in-iter, S lags by one ----
#pragma unroll 1
    for (int it = 0; it < ni - 1; ++it) {
        // S(t+1), own ig — results not needed until the pack below
        float4v s0 = __builtin_amdgcn_mfma_f32_16x16x32_bf16(kf0, qf, m16v, 0, 0, 0);
        float4v s1 = __builtin_amdgcn_mfma_f32_16x16x32_bf16(kf1, qf, m16v, 0, 0, 0);
        // K(t+2) prefetch (tail overreads land in Vg: in-bounds, unused)
        kf0 = *(const short8*)(kb);
        kf1 = *(const short8*)(kb + 512);

        __builtin_amdgcn_s_setprio(1);
        // rotate: load next V group while PV runs on the previous one
#pragma unroll
        for (int k = 0; k < 4; ++k) vfQ[k] = *(const short8*)(vb + (4 + k) * 512);
#pragma unroll
        for (int k = 0; k < 4; ++k)
            acc[k] = __builtin_amdgcn_mfma_f32_16x16x32_bf16(pfc, vfP[k], acc[k], 0, 0, 0);
#pragma unroll
        for (int k = 0; k < 4; ++k) vfP[k] = *(const short8*)(vb + (8 + k) * 512);
#pragma unroll
        for (int k = 0; k < 4; ++k)
            acc[4 + k] = __builtin_amdgcn_mfma_f32_16x16x32_bf16(pfc, vfQ[k], acc[4 + k], 0, 0, 0);
#pragma unroll
        for (int k = 0; k < 4; ++k) vfQ[k] = *(const short8*)(vb + (12 + k) * 512);
#pragma unroll
        for (int k = 0; k < 4; ++k)
            acc[8 + k] = __builtin_amdgcn_mfma_f32_16x16x32_bf16(pfc, vfP[k], acc[8 + k], 0, 0, 0);
#pragma unroll
        for (int k = 0; k < 4; ++k) vfP[k] = *(const short8*)(vb + 8192 + k * 512);  // V(t+1) g0
#pragma unroll
        for (int k = 0; k < 4; ++k)
            acc[12 + k] = __builtin_amdgcn_mfma_f32_16x16x32_bf16(pfc, vfQ[k], acc[12 + k], 0, 0, 0);
        __builtin_amdgcn_s_setprio(0);

        // finish S(t+1): exp2 + rowsum + pack -> pfc (all PV reads of pfc issued)
        {
            float p0 = __builtin_amdgcn_exp2f(s0[0]), p1 = __builtin_amdgcn_exp2f(s0[1]);
            float p2 = __builtin_amdgcn_exp2f(s0[2]), p3 = __builtin_amdgcn_exp2f(s0[3]);
            float p4 = __builtin_amdgcn_exp2f(s1[0]), p5 = __builtin_amdgcn_exp2f(s1[1]);
            float p6 = __builtin_amdgcn_exp2f(s1[2]), p7 = __builtin_amdgcn_exp2f(s1[3]);
            lsc += ((p0 + p1) + (p2 + p3)) + ((p4 + p5) + (p6 + p7));
            union { short8 s8; unsigned u[4]; } pf_;
            pf_.u[0] = cvtpk_bf16(p0, p1);
            pf_.u[1] = cvtpk_bf16(p2, p3);
            pf_.u[2] = cvtpk_bf16(p4, p5);
            pf_.u[3] = cvtpk_bf16(p6, p7);
            pfc = pf_.s8;
        }

        kb += 1024;    // 32 j-rows * 32
        vb += 8192;    // next jblk: 256 c * 32
    }

    // ---- epilogue PV(ni-1): vfP holds g0; rotate g1..g3 ----
#pragma unroll
    for (int k = 0; k < 4; ++k) vfQ[k] = *(const short8*)(vb + (4 + k) * 512);
#pragma unroll
    for (int k = 0; k < 4; ++k)
        acc[k] = __builtin_amdgcn_mfma_f32_16x16x32_bf16(pfc, vfP[k], acc[k], 0, 0, 0);
#pragma unroll
    for (int k = 0; k < 4; ++k) vfP[k] = *(const short8*)(vb + (8 + k) * 512);
#pragma unroll
    for (int k = 0; k < 4; ++k)
        acc[4 + k] = __builtin_amdgcn_mfma_f32_16x16x32_bf16(pfc, vfQ[k], acc[4 + k], 0, 0, 0);
#pragma unroll
    for (int k = 0; k < 4; ++k) vfQ[k] = *(const short8*)(vb + (12 + k) * 512);
#pragma unroll
    for (int k = 0; k < 4; ++k)
        acc[8 + k] = __builtin_amdgcn_mfma_f32_16x16x32_bf16(pfc, vfP[k], acc[8 + k], 0, 0, 0);
#pragma unroll
    for (int k = 0; k < 4; ++k)
        acc[12 + k] = __builtin_amdgcn_mfma_f32_16x16x32_bf16(pfc, vfQ[k], acc[12 + k], 0, 0, 0);

    // ---- epilogue: O partial (bf16, unnormalized) + l per row ----
    // own i-tile: i = w*16 + q*4 + r; c = ct*16 + n — disjoint across waves
    const size_t obase = (size_t)lidx * 16384;
#pragma unroll
    for (int ct = 0; ct < 16; ++ct) {
        int c = ct * 16 + n;
        int i = w * 16 + q * 4;
        int2v pk;
        pk.x = (int)pk_bf16(acc[ct][0], acc[ct][1]);
        pk.y = (int)pk_bf16(acc[ct][2], acc[ct][3]);
        *(int2v*)(Opart + obase + (size_t)c * 64 + i) = pk;
    }
    // row sums: reduce own-ig partial over the 4 q-lanes; wave w owns rows
    // w*16..w*16+15 (disjoint across waves)
    {
        float v = lsc;
        v += __shfl_xor(v, 16, 64);
        v += __shfl_xor(v, 32, 64);
        if (lane < 16)
            lsum[(size_t)lidx * 64 + w * 16 + lane] = v;
    }
}

// ---------------------------------------------------------------------------
// Kernel 3: combine 3 splits + residual, 16B Opart loads.  Byte-identical to
// R13-15.  grid 2048: b=blk&3, rt=(blk>>2)&63, cs=blk>>8.
// out = gam*a*cd + (1-cd) * (sum_s O_s)/(sum_s l_s)
// ---------------------------------------------------------------------------
__launch_bounds__(256, 4)
__global__ void combine_kernel(const float* __restrict__ a_p, const float* __restrict__ c_p,
                               const float* __restrict__ gamma_p,
                               const unsigned short* __restrict__ Opart,
                               const float* __restrict__ lsum, float* __restrict__ out)
{
    __shared__ float invL[64];
    __shared__ float cdl[64];

    const int t   = threadIdx.x;
    const int blk = blockIdx.x;
    const int b   = blk & 3;
    const int rt  = (blk >> 2) & 63;
    const int cs  = blk >> 8;
    const int i0  = rt * 64;

    if (t < 64) {
        float L = 0.f;
#pragma unroll
        for (int s = 0; s < 3; ++s)
            L += lsum[(size_t)((s << 8) | (rt << 2) | b) * 64 + t];
        invL[t] = 1.0f / L;
        cdl[t] = c_p[b * 16384 + rt * 256 + 2 * t];
    }
    __syncthreads();

    const float gam = gamma_p[0];
    const int c  = cs * 32 + (t >> 3);
    const int e8 = (t & 7) * 8;          // i-chunk base
    float o[8];
#pragma unroll
    for (int r = 0; r < 8; ++r) o[r] = 0.f;
#pragma unroll
    for (int s = 0; s < 3; ++s) {
        int idx = (s << 8) | (rt << 2) | b;
        int4v pv = *(const int4v*)(Opart + (size_t)idx * 16384 + (size_t)c * 64 + e8);
#pragma unroll
        for (int h = 0; h < 4; ++h) {
            unsigned u = (unsigned)pv[h];
            o[2 * h]     += bf2f((unsigned short)(u & 0xffffu));
            o[2 * h + 1] += bf2f((unsigned short)(u >> 16));
        }
    }
    size_t gi = (size_t)(b * 256 + c) * 4096 + i0 + e8;
    float4v a0 = *(const float4v*)(a_p + gi);
    float4v a1 = *(const float4v*)(a_p + gi + 4);
    float4v ov0, ov1;
#pragma unroll
    for (int r = 0; r < 4; ++r) {
        float cd0 = cdl[e8 + r],     l0 = invL[e8 + r];
        float cd1 = cdl[e8 + 4 + r], l1 = invL[e8 + 4 + r];
        ov0[r] = gam * a0[r] * cd0 + (1.0f - cd0) * (o[r] * l0);
        ov1[r] = gam * a1[r] * cd1 + (1.0f - cd1) * (o[4 + r] * l1);
    }
    *(float4v*)(out + gi) = ov0;
    *(float4v*)(out + gi + 4) = ov1;
}

// ---------------------------------------------------------------------------
extern "C" void kernel_launch(void* const* d_in, const int* in_sizes, int n_in,
                              void* d_out, int out_size, void* d_ws, size_t ws_size,
                              hipStream_t stream)
{
    const float* a_p   = (const float*)d_in[0];
    const float* b_p   = (const float*)d_in[1];
    const float* c_p   = (const float*)d_in[2];
    const float* wq    = (const float*)d_in[3];
    const float* bq    = (const float*)d_in[4];
    const float* wk    = (const float*)d_in[5];
    const float* bk    = (const float*)d_in[6];
    const float* wv    = (const float*)d_in[7];
    const float* bv    = (const float*)d_in[8];
    const float* gamma = (const float*)d_in[9];
    float* out = (float*)d_out;

    // workspace layout (ushort elems unless noted):
    // Qg 524288 | Kg 524288 | Vg 4194304 | Wbf 81920 | Opart 12582912 | lsum 49152 f32
    unsigned short* Qg    = (unsigned short*)d_ws;
    unsigned short* Kg    = Qg + (size_t)4 * 4096 * 32;
    unsigned short* Vg    = Kg + (size_t)4 * 4096 * 32;
    unsigned short* Wbf   = Vg + (size_t)4 * 256 * 4096;
    unsigned short* Opart = Wbf + (size_t)320 * 256;
    float*          lsum  = (float*)(Opart + (size_t)768 * 16384);

    wcvt_kernel<<<80, 256, 0, stream>>>(wq, wk, wv, Wbf);
    proj_kernel<<<256, 512, 0, stream>>>(a_p, b_p, c_p, bq, bk, bv, Wbf, Qg, Kg, Vg);
    attn_kernel<<<768, 256, 0, stream>>>(Qg, Kg, Vg, Opart, lsum);
    combine_kernel<<<2048, 256, 0, stream>>>(a_p, c_p, gamma, Opart, lsum, out);
}

// Round 17
// 179.319 us; speedup vs baseline: 1.4678x; 1.4678x over previous
//
#include <hip/hip_runtime.h>

#define LOG2E 1.44269504088896340736f

typedef __attribute__((ext_vector_type(8))) short short8;
typedef __attribute__((ext_vector_type(4))) float float4v;
typedef __attribute__((ext_vector_type(2))) float float2v;
typedef __attribute__((ext_vector_type(2))) int int2v;
typedef __attribute__((ext_vector_type(4))) int int4v;

__device__ inline unsigned short f2bf(float f) {
    union { float f; unsigned u; } v; v.f = f;
    unsigned r = v.u + 0x7fffu + ((v.u >> 16) & 1u);
    return (unsigned short)(r >> 16);
}
__device__ inline float bf2f(unsigned short u) {
    union { unsigned u; float f; } v; v.u = ((unsigned)u) << 16;
    return v.f;
}
// pack hi16(a)|hi16(b)<<16 with +0x8000 rounding (2 adds + 1 perm); a = low half
__device__ inline unsigned pk_bf16(float a, float b) {
    union { float f; unsigned u; } ua, ub; ua.f = a; ub.f = b;
    return __builtin_amdgcn_perm(ub.u + 0x8000u, ua.u + 0x8000u, 0x07060302u);
}
// hardware packed cvt: dst = {lo16: bf16(a), hi16: bf16(b)} (RNE), 1 VALU op
__device__ inline unsigned cvtpk_bf16(float a, float b) {
    unsigned r;
    asm("v_cvt_pk_bf16_f32 %0, %1, %2" : "=v"(r) : "v"(a), "v"(b));
    return r;
}

// ---------------------------------------------------------------------------
// Kernel 0: convert weights to bf16, concatenated Wbf[320][256]
// rows 0-31 = wq, 32-63 = wk, 64-319 = wv.  grid 80 x 256.
// ---------------------------------------------------------------------------
__global__ void wcvt_kernel(const float* __restrict__ wq, const float* __restrict__ wk,
                            const float* __restrict__ wv, unsigned short* __restrict__ Wbf)
{
    int idx = blockIdx.x * 256 + threadIdx.x;     // 20480 float4s
    int e4  = idx * 4;
    int row = e4 >> 8, col = e4 & 255;
    const float* src = (row < 32) ? (wq + row * 256 + col)
                     : (row < 64) ? (wk + (row - 32) * 256 + col)
                                  : (wv + (row - 64) * 256 + col);
    float4v v = *(const float4v*)src;
    int2v p;
    p.x = (unsigned)f2bf(v[0]) | ((unsigned)f2bf(v[1]) << 16);
    p.y = (unsigned)f2bf(v[2]) | ((unsigned)f2bf(v[3]) << 16);
    *(int2v*)(Wbf + e4) = p;
}

// ---------------------------------------------------------------------------
// Kernel 1: projections — 64-pixel tiles, grid 256.  Byte-identical to R13-16
// (best measured rest).  Phase 1 COALESCED; Wbf reads; LDS pad 266.
// ---------------------------------------------------------------------------
__launch_bounds__(512, 2)
__global__ void proj_kernel(const float* __restrict__ a_p, const float* __restrict__ b_p,
                            const float* __restrict__ c_p,
                            const float* __restrict__ bq, const float* __restrict__ bk,
                            const float* __restrict__ bv,
                            const unsigned short* __restrict__ Wbf,
                            unsigned short* __restrict__ Qg, unsigned short* __restrict__ Kg,
                            unsigned short* __restrict__ Vg)
{
    __shared__ __align__(16) unsigned short At[64 * 266];   // (i, c) bf16, pad 266
    __shared__ __align__(16) unsigned short Bt[64 * 266];
    __shared__ float bias[320];
    __shared__ float cdl[64];

    const int t    = threadIdx.x;
    const int blk  = blockIdx.x;
    const int b    = blk & 3;
    const int tile = blk >> 2;
    const int i0   = tile * 64;
    const int lane = t & 63;
    const int w    = t >> 6;
    const int q    = lane >> 4;
    const int n    = lane & 15;
    const int it   = w & 3;     // i-tile
    const int mh   = w >> 2;    // m-half (0: mt 0-9, 1: mt 10-19)

    // ---- phase 1: stage a,b tiles transposed to LDS (i, c) bf16, COALESCED ----
    {
        const int arr = t >> 8, tt = t & 255;
        unsigned* dst = (unsigned*)(arr ? Bt : At);
        const float* base = (arr ? b_p : a_p) + (size_t)b * 256 * 4096 + i0;
#pragma unroll
        for (int r = 0; r < 8; ++r) {
            int task = r * 256 + tt;
            int cp = task >> 4, px4 = (task & 15) * 4;
            const float* s0 = base + (size_t)(2 * cp) * 4096 + px4;
            float4v r0 = *(const float4v*)s0;
            float4v r1 = *(const float4v*)(s0 + 4096);
#pragma unroll
            for (int k = 0; k < 4; ++k)
                dst[(px4 + k) * 133 + cp] = pk_bf16(r0[k], r1[k]);
        }
        if (t < 320) bias[t] = (t < 32) ? bq[t] : (t < 64) ? bk[t - 32] : bv[t - 64];
        else if (t < 384) cdl[t - 320] = c_p[b * 16384 + tile * 256 + (t - 320) * 2];
    }
    __syncthreads();

    // ---- phase 2: MFMA (A = Wbf rows, B = X^T) ----
    float4v acc[10];
#pragma unroll
    for (int j = 0; j < 10; ++j) acc[j] = (float4v){0.f, 0.f, 0.f, 0.f};

#pragma unroll 2
    for (int kc = 0; kc < 8; ++kc) {
        short8 xa = *(const short8*)&At[(it * 16 + n) * 266 + kc * 32 + q * 8];
        short8 xb = xa;
        if (mh == 0)
            xb = *(const short8*)&Bt[(it * 16 + n) * 266 + kc * 32 + q * 8];
#pragma unroll
        for (int j = 0; j < 10; ++j) {
            int mt = mh * 10 + j;
            short8 wf = *(const short8*)(Wbf + (size_t)(mt * 16 + n) * 256 + kc * 32 + q * 8);
            short8 bsel = (mt == 2 || mt == 3) ? xb : xa;
            acc[j] = __builtin_amdgcn_mfma_f32_16x16x32_bf16(wf, bsel, acc[j], 0, 0, 0);
        }
    }
    __syncthreads();   // all LDS reads done; At/Bt reusable as staging

    // ---- phase 3a: frags -> LDS staging ----
    unsigned short* QKst = At;   // [i][72] ushort (row 144B, 16B-aligned)
    unsigned short* Vst  = Bt;   // [jb][c][32] ushort = 16384
    {
        const float cdq = cdl[it * 16 + n] * LOG2E;
#pragma unroll
        for (int j = 0; j < 10; ++j) {
            int mt = mh * 10 + j;
            float4v bv4 = *(const float4v*)&bias[mt * 16 + q * 4];
            float v0 = acc[j][0] + bv4[0], v1 = acc[j][1] + bv4[1];
            float v2 = acc[j][2] + bv4[2], v3 = acc[j][3] + bv4[3];
            if (mt < 2) {        // Q: scale by cd*log2e
                v0 *= cdq; v1 *= cdq; v2 *= cdq; v3 *= cdq;
                int2v pk; pk.x = (int)pk_bf16(v0, v1); pk.y = (int)pk_bf16(v2, v3);
                *(int2v*)&QKst[(it * 16 + n) * 72 + mt * 16 + q * 4] = pk;
            } else if (mt < 4) { // K
                int2v pk; pk.x = (int)pk_bf16(v0, v1); pk.y = (int)pk_bf16(v2, v3);
                *(int2v*)&QKst[(it * 16 + n) * 72 + mt * 16 + q * 4] = pk;
            } else {             // V: c = mt*16-64+q*4+r, p fixed per lane
                int p = ((n >> 2) * 8) + ((it & 1) * 4) + (n & 3);
                int cbase = mt * 16 - 64 + q * 4;
                int jb = it >> 1;
                Vst[((jb * 256) + cbase + 0) * 32 + p] = f2bf(v0);
                Vst[((jb * 256) + cbase + 1) * 32 + p] = f2bf(v1);
                Vst[((jb * 256) + cbase + 2) * 32 + p] = f2bf(v2);
                Vst[((jb * 256) + cbase + 3) * 32 + p] = f2bf(v3);
            }
        }
    }
    __syncthreads();

    // ---- phase 3b: coalesced global writes (16B per lane) ----
    {   // Q/K: 64 i x 64 m; thread: i = t>>3, 8-m chunk h8 = t&7
        int i = t >> 3, h8 = t & 7;
        int4v v = *(const int4v*)&QKst[i * 72 + h8 * 8];
        unsigned short* dstp = (h8 < 4)
            ? Qg + (size_t)(b * 4096 + i0 + i) * 32 + h8 * 8
            : Kg + (size_t)(b * 4096 + i0 + i) * 32 + (h8 - 4) * 8;
        *(int4v*)dstp = v;
    }
    {   // V: 32KB flat copy (Vst inner layout == Vg inner layout)
#pragma unroll
        for (int k = 0; k < 4; ++k) {
            int flat = k * 512 + t;              // 16B units
            int4v v = *(const int4v*)&Vst[flat * 8];
            int jb = flat >> 10;                 // 1024 x 16B per jblk
            *(int4v*)(Vg + (size_t)(b * 128 + tile * 2 + jb) * 8192 + (flat & 1023) * 8) = v;
        }
    }
}

// ---------------------------------------------------------------------------
// Kernel 2: flash attention, 3-split, shared softmax, KVBLK=64 (2 j-blocks
// per barrier round).  R14 (57.9us) had 47 barrier round trips; R16's
// barrier-free register partition failed on V-load latency (151us).  This
// keeps R14's partition (wave w: S for own ig only; PV for all ig x own 4
// c-tiles) but AMORTIZES the barrier 2x: per round, S(own) for 2 sub-blocks
// (4 MFMA + 16 exp2), write both P frags, ONE barrier, then a 32-MFMA PV
// cluster (4 ig x 4 ct x 2 sub).  Rounds: {24,24,16}.  LDS 16KB, ~110 arch
// VGPR + 64 AGPR < 170 cap @ 3 blocks/CU.
// ---------------------------------------------------------------------------
__launch_bounds__(256, 3)
__global__ void attn_kernel(const unsigned short* __restrict__ Qg,
                            const unsigned short* __restrict__ Kg,
                            const unsigned short* __restrict__ Vg,
                            unsigned short* __restrict__ Opart, float* __restrict__ lsum)
{
    __shared__ __align__(16) unsigned short Pbuf[2][4][2][64 * 8];  // 16KB

    const int t    = threadIdx.x;
    const int blk  = blockIdx.x;
    const int b    = blk & 3;            // XCD = blk%8 -> b fixed per XCD
    const int rt   = (blk >> 2) & 63;
    const int s    = blk >> 8;           // 0..2
    const int nr   = (s == 2) ? 16 : 24; // 64-row rounds this split
    const int lidx = (s << 8) | (rt << 2) | b;    // logical index for Opart/lsum
    const int i0   = rt * 64;
    const int lane = t & 63;
    const int w    = t >> 6;
    const int q    = lane >> 4;
    const int n    = lane & 15;

    // Q B-frag for OWN i-tile only (ig == w)
    short8 qf = *(const short8*)(Qg + (size_t)(b * 4096 + i0 + w * 16 + n) * 32 + q * 8);

    float4v acc[4][4];   // [ig][ct]
#pragma unroll
    for (int ig = 0; ig < 4; ++ig)
#pragma unroll
        for (int ct = 0; ct < 4; ++ct) acc[ig][ct] = (float4v){0.f, 0.f, 0.f, 0.f};
    float lsc = 0.f;     // rowsum partial for own ig

    const float4v m16v = (float4v){-16.f, -16.f, -16.f, -16.f};

    // split s covers j rows [s*1536, s*1536 + nr*64)
    const unsigned short* kb = Kg + (size_t)(b * 4096 + s * 1536 + n) * 32 + q * 8;
    // wave's own 64-c V slice: [b][jblk][c][p], c = 64w + ct*16 + n, p = q*8..+8
    const unsigned short* vb = Vg + ((size_t)((b * 128 + s * 48) * 256 + w * 64 + n)) * 32 + q * 8;

    // ---- prologue: K(0); S(0,own) both subs -> Pbuf[0]; K(1); barrier ----
    short8 kfs[4];
#pragma unroll
    for (int k = 0; k < 4; ++k) kfs[k] = *(const short8*)(kb + k * 512);

    {
        float4v sA0 = __builtin_amdgcn_mfma_f32_16x16x32_bf16(kfs[0], qf, m16v, 0, 0, 0);
        float4v sA1 = __builtin_amdgcn_mfma_f32_16x16x32_bf16(kfs[1], qf, m16v, 0, 0, 0);
        float4v sB0 = __builtin_amdgcn_mfma_f32_16x16x32_bf16(kfs[2], qf, m16v, 0, 0, 0);
        float4v sB1 = __builtin_amdgcn_mfma_f32_16x16x32_bf16(kfs[3], qf, m16v, 0, 0, 0);
#pragma unroll
        for (int k = 0; k < 4; ++k) kfs[k] = *(const short8*)(kb + 2048 + k * 512);  // K(1)
        float a0 = __builtin_amdgcn_exp2f(sA0[0]), a1 = __builtin_amdgcn_exp2f(sA0[1]);
        float a2 = __builtin_amdgcn_exp2f(sA0[2]), a3 = __builtin_amdgcn_exp2f(sA0[3]);
        float a4 = __builtin_amdgcn_exp2f(sA1[0]), a5 = __builtin_amdgcn_exp2f(sA1[1]);
        float a6 = __builtin_amdgcn_exp2f(sA1[2]), a7 = __builtin_amdgcn_exp2f(sA1[3]);
        float b0 = __builtin_amdgcn_exp2f(sB0[0]), b1 = __builtin_amdgcn_exp2f(sB0[1]);
        float b2 = __builtin_amdgcn_exp2f(sB0[2]), b3 = __builtin_amdgcn_exp2f(sB0[3]);
        float b4 = __builtin_amdgcn_exp2f(sB1[0]), b5 = __builtin_amdgcn_exp2f(sB1[1]);
        float b6 = __builtin_amdgcn_exp2f(sB1[2]), b7 = __builtin_amdgcn_exp2f(sB1[3]);
        lsc += ((a0 + a1) + (a2 + a3)) + ((a4 + a5) + (a6 + a7))
             + ((b0 + b1) + (b2 + b3)) + ((b4 + b5) + (b6 + b7));
        union { short8 s8; unsigned u[4]; } pA_, pB_;
        pA_.u[0] = cvtpk_bf16(a0, a1); pA_.u[1] = cvtpk_bf16(a2, a3);
        pA_.u[2] = cvtpk_bf16(a4, a5); pA_.u[3] = cvtpk_bf16(a6, a7);
        pB_.u[0] = cvtpk_bf16(b0, b1); pB_.u[1] = cvtpk_bf16(b2, b3);
        pB_.u[2] = cvtpk_bf16(b4, b5); pB_.u[3] = cvtpk_bf16(b6, b7);
        *(short8*)&Pbuf[0][w][0][lane * 8] = pA_.s8;
        *(short8*)&Pbuf[0][w][1][lane * 8] = pB_.s8;
    }
    __syncthreads();
    short8 pfc[4][2];
#pragma unroll
    for (int ig = 0; ig < 4; ++ig) {
        pfc[ig][0] = *(const short8*)&Pbuf[0][ig][0][lane * 8];
        pfc[ig][1] = *(const short8*)&Pbuf[0][ig][1][lane * 8];
    }
    kb += 4096;    // points at K(2)

    // ---- main loop: nr-1 rounds; PV(r) in-round, S lags by one round ----
#pragma unroll 1
    for (int r = 0; r < nr - 1; ++r) {
        // S(r+1), own ig, both subs — results not needed until the pack below
        float4v sA0 = __builtin_amdgcn_mfma_f32_16x16x32_bf16(kfs[0], qf, m16v, 0, 0, 0);
        float4v sA1 = __builtin_amdgcn_mfma_f32_16x16x32_bf16(kfs[1], qf, m16v, 0, 0, 0);
        float4v sB0 = __builtin_amdgcn_mfma_f32_16x16x32_bf16(kfs[2], qf, m16v, 0, 0, 0);
        float4v sB1 = __builtin_amdgcn_mfma_f32_16x16x32_bf16(kfs[3], qf, m16v, 0, 0, 0);
        // K(r+2) prefetch (tail overreads land in next split's K / Vg: in-bounds)
#pragma unroll
        for (int k = 0; k < 4; ++k) kfs[k] = *(const short8*)(kb + k * 512);

        __builtin_amdgcn_s_setprio(1);
        // PV(r) sub0: V loads then 16 MFMAs (pfc/vf independent of sA/sB)
        {
            short8 vf[4];
#pragma unroll
            for (int ct = 0; ct < 4; ++ct)
                vf[ct] = *(const short8*)(vb + ct * 512);
#pragma unroll
            for (int ig = 0; ig < 4; ++ig)
#pragma unroll
                for (int ct = 0; ct < 4; ++ct)
                    acc[ig][ct] = __builtin_amdgcn_mfma_f32_16x16x32_bf16(pfc[ig][0], vf[ct], acc[ig][ct], 0, 0, 0);
        }
        // PV(r) sub1
        {
            short8 vf[4];
#pragma unroll
            for (int ct = 0; ct < 4; ++ct)
                vf[ct] = *(const short8*)(vb + 8192 + ct * 512);
#pragma unroll
            for (int ig = 0; ig < 4; ++ig)
#pragma unroll
                for (int ct = 0; ct < 4; ++ct)
                    acc[ig][ct] = __builtin_amdgcn_mfma_f32_16x16x32_bf16(pfc[ig][1], vf[ct], acc[ig][ct], 0, 0, 0);
        }
        __builtin_amdgcn_s_setprio(0);

        // finish S(r+1): exp2 + rowsum + pack -> Pbuf[(r+1)&1][w][0/1]
        {
            float a0 = __builtin_amdgcn_exp2f(sA0[0]), a1 = __builtin_amdgcn_exp2f(sA0[1]);
            float a2 = __builtin_amdgcn_exp2f(sA0[2]), a3 = __builtin_amdgcn_exp2f(sA0[3]);
            float a4 = __builtin_amdgcn_exp2f(sA1[0]), a5 = __builtin_amdgcn_exp2f(sA1[1]);
            float a6 = __builtin_amdgcn_exp2f(sA1[2]), a7 = __builtin_amdgcn_exp2f(sA1[3]);
            float b0 = __builtin_amdgcn_exp2f(sB0[0]), b1 = __builtin_amdgcn_exp2f(sB0[1]);
            float b2 = __builtin_amdgcn_exp2f(sB0[2]), b3 = __builtin_amdgcn_exp2f(sB0[3]);
            float b4 = __builtin_amdgcn_exp2f(sB1[0]), b5 = __builtin_amdgcn_exp2f(sB1[1]);
            float b6 = __builtin_amdgcn_exp2f(sB1[2]), b7 = __builtin_amdgcn_exp2f(sB1[3]);
            lsc += ((a0 + a1) + (a2 + a3)) + ((a4 + a5) + (a6 + a7))
                 + ((b0 + b1) + (b2 + b3)) + ((b4 + b5) + (b6 + b7));
            union { short8 s8; unsigned u[4]; } pA_, pB_;
            pA_.u[0] = cvtpk_bf16(a0, a1); pA_.u[1] = cvtpk_bf16(a2, a3);
            pA_.u[2] = cvtpk_bf16(a4, a5); pA_.u[3] = cvtpk_bf16(a6, a7);
            pB_.u[0] = cvtpk_bf16(b0, b1); pB_.u[1] = cvtpk_bf16(b2, b3);
            pB_.u[2] = cvtpk_bf16(b4, b5); pB_.u[3] = cvtpk_bf16(b6, b7);
            *(short8*)&Pbuf[(r + 1) & 1][w][0][lane * 8] = pA_.s8;
            *(short8*)&Pbuf[(r + 1) & 1][w][1][lane * 8] = pB_.s8;
        }
        __syncthreads();
#pragma unroll
        for (int ig = 0; ig < 4; ++ig) {
            pfc[ig][0] = *(const short8*)&Pbuf[(r + 1) & 1][ig][0][lane * 8];
            pfc[ig][1] = *(const short8*)&Pbuf[(r + 1) & 1][ig][1][lane * 8];
        }

        kb += 2048;    // 64 j-rows * 32
        vb += 16384;   // 2 jblks: 2 * 256 c * 32
    }

    // ---- epilogue PV(nr-1): both subs ----
    {
        short8 vf[4];
#pragma unroll
        for (int ct = 0; ct < 4; ++ct)
            vf[ct] = *(const short8*)(vb + ct * 512);
#pragma unroll
        for (int ig = 0; ig < 4; ++ig)
#pragma unroll
            for (int ct = 0; ct < 4; ++ct)
                acc[ig][ct] = __builtin_amdgcn_mfma_f32_16x16x32_bf16(pfc[ig][0], vf[ct], acc[ig][ct], 0, 0, 0);
#pragma unroll
        for (int ct = 0; ct < 4; ++ct)
            vf[ct] = *(const short8*)(vb + 8192 + ct * 512);
#pragma unroll
        for (int ig = 0; ig < 4; ++ig)
#pragma unroll
            for (int ct = 0; ct < 4; ++ct)
                acc[ig][ct] = __builtin_amdgcn_mfma_f32_16x16x32_bf16(pfc[ig][1], vf[ct], acc[ig][ct], 0, 0, 0);
    }

    // ---- epilogue: O partial (bf16, unnormalized) + l per row ----
    const size_t obase = (size_t)lidx * 16384;
#pragma unroll
    for (int ig = 0; ig < 4; ++ig)
#pragma unroll
        for (int ct = 0; ct < 4; ++ct) {
            int c = w * 64 + ct * 16 + n;
            int i = ig * 16 + q * 4;
            int2v pk;
            pk.x = (int)pk_bf16(acc[ig][ct][0], acc[ig][ct][1]);
            pk.y = (int)pk_bf16(acc[ig][ct][2], acc[ig][ct][3]);
            *(int2v*)(Opart + obase + (size_t)c * 64 + i) = pk;
        }
    // row sums: reduce own-ig partial over the 4 q-lanes; wave w owns rows
    // w*16..w*16+15 (disjoint across waves)
    {
        float v = lsc;
        v += __shfl_xor(v, 16, 64);
        v += __shfl_xor(v, 32, 64);
        if (lane < 16)
            lsum[(size_t)lidx * 64 + w * 16 + lane] = v;
    }
}

// ---------------------------------------------------------------------------
// Kernel 3: combine 3 splits + residual, 16B Opart loads.  Byte-identical to
// R13-16.  grid 2048: b=blk&3, rt=(blk>>2)&63, cs=blk>>8.
// out = gam*a*cd + (1-cd) * (sum_s O_s)/(sum_s l_s)
// ---------------------------------------------------------------------------
__launch_bounds__(256, 4)
__global__ void combine_kernel(const float* __restrict__ a_p, const float* __restrict__ c_p,
                               const float* __restrict__ gamma_p,
                               const unsigned short* __restrict__ Opart,
                               const float* __restrict__ lsum, float* __restrict__ out)
{
    __shared__ float invL[64];
    __shared__ float cdl[64];

    const int t   = threadIdx.x;
    const int blk = blockIdx.x;
    const int b   = blk & 3;
    const int rt  = (blk >> 2) & 63;
    const int cs  = blk >> 8;
    const int i0  = rt * 64;

    if (t < 64) {
        float L = 0.f;
#pragma unroll
        for (int s = 0; s < 3; ++s)
            L += lsum[(size_t)((s << 8) | (rt << 2) | b) * 64 + t];
        invL[t] = 1.0f / L;
        cdl[t] = c_p[b * 16384 + rt * 256 + 2 * t];
    }
    __syncthreads();

    const float gam = gamma_p[0];
    const int c  = cs * 32 + (t >> 3);
    const int e8 = (t & 7) * 8;          // i-chunk base
    float o[8];
#pragma unroll
    for (int r = 0; r < 8; ++r) o[r] = 0.f;
#pragma unroll
    for (int s = 0; s < 3; ++s) {
        int idx = (s << 8) | (rt << 2) | b;
        int4v pv = *(const int4v*)(Opart + (size_t)idx * 16384 + (size_t)c * 64 + e8);
#pragma unroll
        for (int h = 0; h < 4; ++h) {
            unsigned u = (unsigned)pv[h];
            o[2 * h]     += bf2f((unsigned short)(u & 0xffffu));
            o[2 * h + 1] += bf2f((unsigned short)(u >> 16));
        }
    }
    size_t gi = (size_t)(b * 256 + c) * 4096 + i0 + e8;
    float4v a0 = *(const float4v*)(a_p + gi);
    float4v a1 = *(const float4v*)(a_p + gi + 4);
    float4v ov0, ov1;
#pragma unroll
    for (int r = 0; r < 4; ++r) {
        float cd0 = cdl[e8 + r],     l0 = invL[e8 + r];
        float cd1 = cdl[e8 + 4 + r], l1 = invL[e8 + 4 + r];
        ov0[r] = gam * a0[r] * cd0 + (1.0f - cd0) * (o[r] * l0);
        ov1[r] = gam * a1[r] * cd1 + (1.0f - cd1) * (o[4 + r] * l1);
    }
    *(float4v*)(out + gi) = ov0;
    *(float4v*)(out + gi + 4) = ov1;
}

// ---------------------------------------------------------------------------
extern "C" void kernel_launch(void* const* d_in, const int* in_sizes, int n_in,
                              void* d_out, int out_size, void* d_ws, size_t ws_size,
                              hipStream_t stream)
{
    const float* a_p   = (const float*)d_in[0];
    const float* b_p   = (const float*)d_in[1];
    const float* c_p   = (const float*)d_in[2];
    const float* wq    = (const float*)d_in[3];
    const float* bq    = (const float*)d_in[4];
    const float* wk    = (const float*)d_in[5];
    const float* bk    = (const float*)d_in[6];
    const float* wv    = (const float*)d_in[7];
    const float* bv    = (const float*)d_in[8];
    const float* gamma = (const float*)d_in[9];
    float* out = (float*)d_out;

    // workspace layout (ushort elems unless noted):
    // Qg 524288 | Kg 524288 | Vg 4194304 | Wbf 81920 | Opart 12582912 | lsum 49152 f32
    unsigned short* Qg    = (unsigned short*)d_ws;
    unsigned short* Kg    = Qg + (size_t)4 * 4096 * 32;
    unsigned short* Vg    = Kg + (size_t)4 * 4096 * 32;
    unsigned short* Wbf   = Vg + (size_t)4 * 256 * 4096;
    unsigned short* Opart = Wbf + (size_t)320 * 256;
    float*          lsum  = (float*)(Opart + (size_t)768 * 16384);

    wcvt_kernel<<<80, 256, 0, stream>>>(wq, wk, wv, Wbf);
    proj_kernel<<<256, 512, 0, stream>>>(a_p, b_p, c_p, bq, bk, bv, Wbf, Qg, Kg, Vg);
    attn_kernel<<<768, 256, 0, stream>>>(Qg, Kg, Vg, Opart, lsum);
    combine_kernel<<<2048, 256, 0, stream>>>(a_p, c_p, gamma, Opart, lsum, out);
}

// Round 18
// 175.263 us; speedup vs baseline: 1.5018x; 1.0231x over previous
//
#include <hip/hip_runtime.h>

#define LOG2E 1.44269504088896340736f

typedef __attribute__((ext_vector_type(8))) short short8;
typedef __attribute__((ext_vector_type(4))) float float4v;
typedef __attribute__((ext_vector_type(2))) float float2v;
typedef __attribute__((ext_vector_type(2))) int int2v;
typedef __attribute__((ext_vector_type(4))) int int4v;

__device__ inline unsigned short f2bf(float f) {
    union { float f; unsigned u; } v; v.f = f;
    unsigned r = v.u + 0x7fffu + ((v.u >> 16) & 1u);
    return (unsigned short)(r >> 16);
}
__device__ inline float bf2f(unsigned short u) {
    union { unsigned u; float f; } v; v.u = ((unsigned)u) << 16;
    return v.f;
}
// pack hi16(a)|hi16(b)<<16 with +0x8000 rounding (2 adds + 1 perm); a = low half
__device__ inline unsigned pk_bf16(float a, float b) {
    union { float f; unsigned u; } ua, ub; ua.f = a; ub.f = b;
    return __builtin_amdgcn_perm(ub.u + 0x8000u, ua.u + 0x8000u, 0x07060302u);
}
// hardware packed cvt: dst = {lo16: bf16(a), hi16: bf16(b)} (RNE), 1 VALU op
__device__ inline unsigned cvtpk_bf16(float a, float b) {
    unsigned r;
    asm("v_cvt_pk_bf16_f32 %0, %1, %2" : "=v"(r) : "v"(a), "v"(b));
    return r;
}

// ---------------------------------------------------------------------------
// Kernel 0: convert weights to bf16, concatenated Wbf[320][256]
// rows 0-31 = wq, 32-63 = wk, 64-319 = wv.  grid 80 x 256.
// ---------------------------------------------------------------------------
__global__ void wcvt_kernel(const float* __restrict__ wq, const float* __restrict__ wk,
                            const float* __restrict__ wv, unsigned short* __restrict__ Wbf)
{
    int idx = blockIdx.x * 256 + threadIdx.x;     // 20480 float4s
    int e4  = idx * 4;
    int row = e4 >> 8, col = e4 & 255;
    const float* src = (row < 32) ? (wq + row * 256 + col)
                     : (row < 64) ? (wk + (row - 32) * 256 + col)
                                  : (wv + (row - 64) * 256 + col);
    float4v v = *(const float4v*)src;
    int2v p;
    p.x = (unsigned)f2bf(v[0]) | ((unsigned)f2bf(v[1]) << 16);
    p.y = (unsigned)f2bf(v[2]) | ((unsigned)f2bf(v[3]) << 16);
    *(int2v*)(Wbf + e4) = p;
}

// ---------------------------------------------------------------------------
// Kernel 1: projections — 64-pixel tiles, grid 256.  Byte-identical to R13
// (best measured rest).  Phase 1 COALESCED; Wbf reads; LDS pad 266.
// ---------------------------------------------------------------------------
__launch_bounds__(512, 2)
__global__ void proj_kernel(const float* __restrict__ a_p, const float* __restrict__ b_p,
                            const float* __restrict__ c_p,
                            const float* __restrict__ bq, const float* __restrict__ bk,
                            const float* __restrict__ bv,
                            const unsigned short* __restrict__ Wbf,
                            unsigned short* __restrict__ Qg, unsigned short* __restrict__ Kg,
                            unsigned short* __restrict__ Vg)
{
    __shared__ __align__(16) unsigned short At[64 * 266];   // (i, c) bf16, pad 266
    __shared__ __align__(16) unsigned short Bt[64 * 266];
    __shared__ float bias[320];
    __shared__ float cdl[64];

    const int t    = threadIdx.x;
    const int blk  = blockIdx.x;
    const int b    = blk & 3;
    const int tile = blk >> 2;
    const int i0   = tile * 64;
    const int lane = t & 63;
    const int w    = t >> 6;
    const int q    = lane >> 4;
    const int n    = lane & 15;
    const int it   = w & 3;     // i-tile
    const int mh   = w >> 2;    // m-half (0: mt 0-9, 1: mt 10-19)

    // ---- phase 1: stage a,b tiles transposed to LDS (i, c) bf16, COALESCED ----
    {
        const int arr = t >> 8, tt = t & 255;
        unsigned* dst = (unsigned*)(arr ? Bt : At);
        const float* base = (arr ? b_p : a_p) + (size_t)b * 256 * 4096 + i0;
#pragma unroll
        for (int r = 0; r < 8; ++r) {
            int task = r * 256 + tt;
            int cp = task >> 4, px4 = (task & 15) * 4;
            const float* s0 = base + (size_t)(2 * cp) * 4096 + px4;
            float4v r0 = *(const float4v*)s0;
            float4v r1 = *(const float4v*)(s0 + 4096);
#pragma unroll
            for (int k = 0; k < 4; ++k)
                dst[(px4 + k) * 133 + cp] = pk_bf16(r0[k], r1[k]);
        }
        if (t < 320) bias[t] = (t < 32) ? bq[t] : (t < 64) ? bk[t - 32] : bv[t - 64];
        else if (t < 384) cdl[t - 320] = c_p[b * 16384 + tile * 256 + (t - 320) * 2];
    }
    __syncthreads();

    // ---- phase 2: MFMA (A = Wbf rows, B = X^T) ----
    float4v acc[10];
#pragma unroll
    for (int j = 0; j < 10; ++j) acc[j] = (float4v){0.f, 0.f, 0.f, 0.f};

#pragma unroll 2
    for (int kc = 0; kc < 8; ++kc) {
        short8 xa = *(const short8*)&At[(it * 16 + n) * 266 + kc * 32 + q * 8];
        short8 xb = xa;
        if (mh == 0)
            xb = *(const short8*)&Bt[(it * 16 + n) * 266 + kc * 32 + q * 8];
#pragma unroll
        for (int j = 0; j < 10; ++j) {
            int mt = mh * 10 + j;
            short8 wf = *(const short8*)(Wbf + (size_t)(mt * 16 + n) * 256 + kc * 32 + q * 8);
            short8 bsel = (mt == 2 || mt == 3) ? xb : xa;
            acc[j] = __builtin_amdgcn_mfma_f32_16x16x32_bf16(wf, bsel, acc[j], 0, 0, 0);
        }
    }
    __syncthreads();   // all LDS reads done; At/Bt reusable as staging

    // ---- phase 3a: frags -> LDS staging ----
    unsigned short* QKst = At;   // [i][72] ushort (row 144B, 16B-aligned)
    unsigned short* Vst  = Bt;   // [jb][c][32] ushort = 16384
    {
        const float cdq = cdl[it * 16 + n] * LOG2E;
#pragma unroll
        for (int j = 0; j < 10; ++j) {
            int mt = mh * 10 + j;
            float4v bv4 = *(const float4v*)&bias[mt * 16 + q * 4];
            float v0 = acc[j][0] + bv4[0], v1 = acc[j][1] + bv4[1];
            float v2 = acc[j][2] + bv4[2], v3 = acc[j][3] + bv4[3];
            if (mt < 2) {        // Q: scale by cd*log2e
                v0 *= cdq; v1 *= cdq; v2 *= cdq; v3 *= cdq;
                int2v pk; pk.x = (int)pk_bf16(v0, v1); pk.y = (int)pk_bf16(v2, v3);
                *(int2v*)&QKst[(it * 16 + n) * 72 + mt * 16 + q * 4] = pk;
            } else if (mt < 4) { // K
                int2v pk; pk.x = (int)pk_bf16(v0, v1); pk.y = (int)pk_bf16(v2, v3);
                *(int2v*)&QKst[(it * 16 + n) * 72 + mt * 16 + q * 4] = pk;
            } else {             // V: c = mt*16-64+q*4+r, p fixed per lane
                int p = ((n >> 2) * 8) + ((it & 1) * 4) + (n & 3);
                int cbase = mt * 16 - 64 + q * 4;
                int jb = it >> 1;
                Vst[((jb * 256) + cbase + 0) * 32 + p] = f2bf(v0);
                Vst[((jb * 256) + cbase + 1) * 32 + p] = f2bf(v1);
                Vst[((jb * 256) + cbase + 2) * 32 + p] = f2bf(v2);
                Vst[((jb * 256) + cbase + 3) * 32 + p] = f2bf(v3);
            }
        }
    }
    __syncthreads();

    // ---- phase 3b: coalesced global writes (16B per lane) ----
    {   // Q/K: 64 i x 64 m; thread: i = t>>3, 8-m chunk h8 = t&7
        int i = t >> 3, h8 = t & 7;
        int4v v = *(const int4v*)&QKst[i * 72 + h8 * 8];
        unsigned short* dstp = (h8 < 4)
            ? Qg + (size_t)(b * 4096 + i0 + i) * 32 + h8 * 8
            : Kg + (size_t)(b * 4096 + i0 + i) * 32 + (h8 - 4) * 8;
        *(int4v*)dstp = v;
    }
    {   // V: 32KB flat copy (Vst inner layout == Vg inner layout)
#pragma unroll
        for (int k = 0; k < 4; ++k) {
            int flat = k * 512 + t;              // 16B units
            int4v v = *(const int4v*)&Vst[flat * 8];
            int jb = flat >> 10;                 // 1024 x 16B per jblk
            *(int4v*)(Vg + (size_t)(b * 128 + tile * 2 + jb) * 8192 + (flat & 1023) * 8) = v;
        }
    }
}

// ---------------------------------------------------------------------------
// Kernel 2: flash attention, 3-split {48,48,32}, pipelined, SHARED SOFTMAX.
// Byte-identical to R14 (session-best attn: 57.9 us).  Wave w computes S only
// for ig==w (2 S-MFMA + 8 exp2 + 4 cvtpk), shares pf via double-buffered LDS
// (8KB), 1 barrier/iter; V(t+1)/K(t+2) prefetched a full iteration ahead.
// Ledger: lds_barrier = null (R15), KVBLK=64 = -5us (R17, loses V lead),
// register partition = -93us (R16), redundant softmax = -6us (R13).
// ---------------------------------------------------------------------------
__launch_bounds__(256, 3)
__global__ void attn_kernel(const unsigned short* __restrict__ Qg,
                            const unsigned short* __restrict__ Kg,
                            const unsigned short* __restrict__ Vg,
                            unsigned short* __restrict__ Opart, float* __restrict__ lsum)
{
    __shared__ __align__(16) unsigned short Pbuf[2][4][64 * 8];  // 8KB

    const int t    = threadIdx.x;
    const int blk  = blockIdx.x;
    const int b    = blk & 3;            // XCD = blk%8 -> b fixed per XCD
    const int rt   = (blk >> 2) & 63;
    const int s    = blk >> 8;           // 0..2
    const int ni   = (s == 2) ? 32 : 48; // iters this split
    const int lidx = (s << 8) | (rt << 2) | b;    // logical index for Opart/lsum
    const int i0   = rt * 64;
    const int lane = t & 63;
    const int w    = t >> 6;
    const int q    = lane >> 4;
    const int n    = lane & 15;

    // Q B-frag for OWN i-tile only (ig == w)
    short8 qf = *(const short8*)(Qg + (size_t)(b * 4096 + i0 + w * 16 + n) * 32 + q * 8);

    float4v acc[4][4];   // [ig][ct]
#pragma unroll
    for (int ig = 0; ig < 4; ++ig)
#pragma unroll
        for (int ct = 0; ct < 4; ++ct) acc[ig][ct] = (float4v){0.f, 0.f, 0.f, 0.f};
    float lsc = 0.f;     // rowsum partial for own ig

    const float4v m16v = (float4v){-16.f, -16.f, -16.f, -16.f};

    // split s covers j rows [s*1536, s*1536 + ni*32)
    const unsigned short* kb = Kg + (size_t)(b * 4096 + s * 1536 + n) * 32 + q * 8;
    // wave's own 64-c V slice: [b][jblk][c][p], c = 64w + ct*16 + n, p = q*8..+8
    const unsigned short* vb = Vg + ((size_t)((b * 128 + s * 48) * 256 + w * 64 + n)) * 32 + q * 8;

    // ---- prologue: V(0), K(0); S(0,own) -> Pbuf[0]; K(1); pfc <- Pbuf[0] ----
    short8 vf[4];
#pragma unroll
    for (int ct = 0; ct < 4; ++ct)
        vf[ct] = *(const short8*)(vb + ct * 512);
    short8 kf0 = *(const short8*)(kb);
    short8 kf1 = *(const short8*)(kb + 512);

    {
        float4v s0 = __builtin_amdgcn_mfma_f32_16x16x32_bf16(kf0, qf, m16v, 0, 0, 0);
        float4v s1 = __builtin_amdgcn_mfma_f32_16x16x32_bf16(kf1, qf, m16v, 0, 0, 0);
        kf0 = *(const short8*)(kb + 1024);   // K(1)
        kf1 = *(const short8*)(kb + 1536);
        float p0 = __builtin_amdgcn_exp2f(s0[0]), p1 = __builtin_amdgcn_exp2f(s0[1]);
        float p2 = __builtin_amdgcn_exp2f(s0[2]), p3 = __builtin_amdgcn_exp2f(s0[3]);
        float p4 = __builtin_amdgcn_exp2f(s1[0]), p5 = __builtin_amdgcn_exp2f(s1[1]);
        float p6 = __builtin_amdgcn_exp2f(s1[2]), p7 = __builtin_amdgcn_exp2f(s1[3]);
        lsc += ((p0 + p1) + (p2 + p3)) + ((p4 + p5) + (p6 + p7));
        union { short8 s8; unsigned u[4]; } pf_;
        pf_.u[0] = cvtpk_bf16(p0, p1);   // k = jt*4 + r order (matches V perm)
        pf_.u[1] = cvtpk_bf16(p2, p3);
        pf_.u[2] = cvtpk_bf16(p4, p5);
        pf_.u[3] = cvtpk_bf16(p6, p7);
        *(short8*)&Pbuf[0][w][lane * 8] = pf_.s8;
    }
    __syncthreads();
    short8 pfc[4];
#pragma unroll
    for (int ig = 0; ig < 4; ++ig)
        pfc[ig] = *(const short8*)&Pbuf[0][ig][lane * 8];

    kb += 2048;    // points at K(2)
    vb += 8192;    // points at V(1)

    // ---- main loop: ni-1 iters, PV lags S by one ----
#pragma unroll 1
    for (int it = 0; it < ni - 1; ++it) {
        // S(t+1), own ig — results not needed until the pack below
        float4v s0 = __builtin_amdgcn_mfma_f32_16x16x32_bf16(kf0, qf, m16v, 0, 0, 0);
        float4v s1 = __builtin_amdgcn_mfma_f32_16x16x32_bf16(kf1, qf, m16v, 0, 0, 0);
        // K(t+2) prefetch (tail overreads land in next split's K / Vg: in-bounds)
        kf0 = *(const short8*)(kb);
        kf1 = *(const short8*)(kb + 512);

        // PV(t) — independent of s0/s1 and of this iter's Pbuf write
        __builtin_amdgcn_s_setprio(1);
#pragma unroll
        for (int ig = 0; ig < 4; ++ig)
#pragma unroll
            for (int ct = 0; ct < 4; ++ct)
                acc[ig][ct] = __builtin_amdgcn_mfma_f32_16x16x32_bf16(pfc[ig], vf[ct], acc[ig][ct], 0, 0, 0);
        __builtin_amdgcn_s_setprio(0);

        // V(t+1) loads (WAR on vf after PV issue)
#pragma unroll
        for (int ct = 0; ct < 4; ++ct)
            vf[ct] = *(const short8*)(vb + ct * 512);

        // finish S(t+1): exp2 + rowsum + pack -> Pbuf[(t+1)&1][w]
        {
            float p0 = __builtin_amdgcn_exp2f(s0[0]), p1 = __builtin_amdgcn_exp2f(s0[1]);
            float p2 = __builtin_amdgcn_exp2f(s0[2]), p3 = __builtin_amdgcn_exp2f(s0[3]);
            float p4 = __builtin_amdgcn_exp2f(s1[0]), p5 = __builtin_amdgcn_exp2f(s1[1]);
            float p6 = __builtin_amdgcn_exp2f(s1[2]), p7 = __builtin_amdgcn_exp2f(s1[3]);
            lsc += ((p0 + p1) + (p2 + p3)) + ((p4 + p5) + (p6 + p7));
            union { short8 s8; unsigned u[4]; } pf_;
            pf_.u[0] = cvtpk_bf16(p0, p1);
            pf_.u[1] = cvtpk_bf16(p2, p3);
            pf_.u[2] = cvtpk_bf16(p4, p5);
            pf_.u[3] = cvtpk_bf16(p6, p7);
            *(short8*)&Pbuf[(it + 1) & 1][w][lane * 8] = pf_.s8;
        }
        __syncthreads();
#pragma unroll
        for (int ig = 0; ig < 4; ++ig)
            pfc[ig] = *(const short8*)&Pbuf[(it + 1) & 1][ig][lane * 8];

        kb += 1024;    // 32 j-rows * 32
        vb += 8192;    // next jblk: 256 c * 32
    }

    // ---- epilogue PV(ni-1) ----
#pragma unroll
    for (int ig = 0; ig < 4; ++ig)
#pragma unroll
        for (int ct = 0; ct < 4; ++ct)
            acc[ig][ct] = __builtin_amdgcn_mfma_f32_16x16x32_bf16(pfc[ig], vf[ct], acc[ig][ct], 0, 0, 0);

    // ---- epilogue: O partial (bf16, unnormalized) + l per row ----
    const size_t obase = (size_t)lidx * 16384;
#pragma unroll
    for (int ig = 0; ig < 4; ++ig)
#pragma unroll
        for (int ct = 0; ct < 4; ++ct) {
            int c = w * 64 + ct * 16 + n;
            int i = ig * 16 + q * 4;
            int2v pk;
            pk.x = (int)pk_bf16(acc[ig][ct][0], acc[ig][ct][1]);
            pk.y = (int)pk_bf16(acc[ig][ct][2], acc[ig][ct][3]);
            *(int2v*)(Opart + obase + (size_t)c * 64 + i) = pk;
        }
    // row sums: reduce own-ig partial over the 4 q-lanes; wave w owns rows
    // w*16..w*16+15 (disjoint across waves)
    {
        float v = lsc;
        v += __shfl_xor(v, 16, 64);
        v += __shfl_xor(v, 32, 64);
        if (lane < 16)
            lsum[(size_t)lidx * 64 + w * 16 + lane] = v;
    }
}

// ---------------------------------------------------------------------------
// Kernel 3: combine 3 splits + residual, 16B Opart loads.  Byte-identical to
// R13/14.  grid 2048: b=blk&3, rt=(blk>>2)&63, cs=blk>>8.
// out = gam*a*cd + (1-cd) * (sum_s O_s)/(sum_s l_s)
// ---------------------------------------------------------------------------
__launch_bounds__(256, 4)
__global__ void combine_kernel(const float* __restrict__ a_p, const float* __restrict__ c_p,
                               const float* __restrict__ gamma_p,
                               const unsigned short* __restrict__ Opart,
                               const float* __restrict__ lsum, float* __restrict__ out)
{
    __shared__ float invL[64];
    __shared__ float cdl[64];

    const int t   = threadIdx.x;
    const int blk = blockIdx.x;
    const int b   = blk & 3;
    const int rt  = (blk >> 2) & 63;
    const int cs  = blk >> 8;
    const int i0  = rt * 64;

    if (t < 64) {
        float L = 0.f;
#pragma unroll
        for (int s = 0; s < 3; ++s)
            L += lsum[(size_t)((s << 8) | (rt << 2) | b) * 64 + t];
        invL[t] = 1.0f / L;
        cdl[t] = c_p[b * 16384 + rt * 256 + 2 * t];
    }
    __syncthreads();

    const float gam = gamma_p[0];
    const int c  = cs * 32 + (t >> 3);
    const int e8 = (t & 7) * 8;          // i-chunk base
    float o[8];
#pragma unroll
    for (int r = 0; r < 8; ++r) o[r] = 0.f;
#pragma unroll
    for (int s = 0; s < 3; ++s) {
        int idx = (s << 8) | (rt << 2) | b;
        int4v pv = *(const int4v*)(Opart + (size_t)idx * 16384 + (size_t)c * 64 + e8);
#pragma unroll
        for (int h = 0; h < 4; ++h) {
            unsigned u = (unsigned)pv[h];
            o[2 * h]     += bf2f((unsigned short)(u & 0xffffu));
            o[2 * h + 1] += bf2f((unsigned short)(u >> 16));
        }
    }
    size_t gi = (size_t)(b * 256 + c) * 4096 + i0 + e8;
    float4v a0 = *(const float4v*)(a_p + gi);
    float4v a1 = *(const float4v*)(a_p + gi + 4);
    float4v ov0, ov1;
#pragma unroll
    for (int r = 0; r < 4; ++r) {
        float cd0 = cdl[e8 + r],     l0 = invL[e8 + r];
        float cd1 = cdl[e8 + 4 + r], l1 = invL[e8 + 4 + r];
        ov0[r] = gam * a0[r] * cd0 + (1.0f - cd0) * (o[r] * l0);
        ov1[r] = gam * a1[r] * cd1 + (1.0f - cd1) * (o[4 + r] * l1);
    }
    *(float4v*)(out + gi) = ov0;
    *(float4v*)(out + gi + 4) = ov1;
}

// ---------------------------------------------------------------------------
extern "C" void kernel_launch(void* const* d_in, const int* in_sizes, int n_in,
                              void* d_out, int out_size, void* d_ws, size_t ws_size,
                              hipStream_t stream)
{
    const float* a_p   = (const float*)d_in[0];
    const float* b_p   = (const float*)d_in[1];
    const float* c_p   = (const float*)d_in[2];
    const float* wq    = (const float*)d_in[3];
    const float* bq    = (const float*)d_in[4];
    const float* wk    = (const float*)d_in[5];
    const float* bk    = (const float*)d_in[6];
    const float* wv    = (const float*)d_in[7];
    const float* bv    = (const float*)d_in[8];
    const float* gamma = (const float*)d_in[9];
    float* out = (float*)d_out;

    // workspace layout (ushort elems unless noted):
    // Qg 524288 | Kg 524288 | Vg 4194304 | Wbf 81920 | Opart 12582912 | lsum 49152 f32
    unsigned short* Qg    = (unsigned short*)d_ws;
    unsigned short* Kg    = Qg + (size_t)4 * 4096 * 32;
    unsigned short* Vg    = Kg + (size_t)4 * 4096 * 32;
    unsigned short* Wbf   = Vg + (size_t)4 * 256 * 4096;
    unsigned short* Opart = Wbf + (size_t)320 * 256;
    float*          lsum  = (float*)(Opart + (size_t)768 * 16384);

    wcvt_kernel<<<80, 256, 0, stream>>>(wq, wk, wv, Wbf);
    proj_kernel<<<256, 512, 0, stream>>>(a_p, b_p, c_p, bq, bk, bv, Wbf, Qg, Kg, Vg);
    attn_kernel<<<768, 256, 0, stream>>>(Qg, Kg, Vg, Opart, lsum);
    combine_kernel<<<2048, 256, 0, stream>>>(a_p, c_p, gamma, Opart, lsum, out);
}